// Round 1
// baseline (201.690 us; speedup 1.0000x reference)
//
#include <hip/hip_runtime.h>

// Dynamic voxelization: coors[d, i] = valid ? floor((p[i,d]-mn[d])/vs[d]) : -1
// Memory-bound streaming kernel: 128 MB read + 96 MB write, no reuse.
// One thread per point: float4 load (coalesced 16B/lane), 3 coalesced int stores.

#define VS_X 0.05f
#define VS_Y 0.05f
#define VS_Z 0.1f
#define MN_X 0.0f
#define MN_Y -40.0f
#define MN_Z -3.0f
#define GX 1408
#define GY 1600
#define GZ 40

__global__ __launch_bounds__(256) void voxelize_kernel(
    const float4* __restrict__ points, int* __restrict__ out, int n) {
    int i = blockIdx.x * blockDim.x + threadIdx.x;
    if (i >= n) return;

    float4 p = points[i];  // (x, y, z, intensity)

    // Match reference exactly: fp32 subtract, fp32 divide, floor, trunc-to-int.
    int cx = (int)floorf((p.x - MN_X) / VS_X);
    int cy = (int)floorf((p.y - MN_Y) / VS_Y);
    int cz = (int)floorf((p.z - MN_Z) / VS_Z);

    bool valid = (cx >= 0) & (cx < GX) & (cy >= 0) & (cy < GY) & (cz >= 0) & (cz < GZ);

    out[i]         = valid ? cx : -1;
    out[n + i]     = valid ? cy : -1;
    out[2 * n + i] = valid ? cz : -1;
}

extern "C" void kernel_launch(void* const* d_in, const int* in_sizes, int n_in,
                              void* d_out, int out_size, void* d_ws, size_t ws_size,
                              hipStream_t stream) {
    const float4* points = (const float4*)d_in[0];
    int* out = (int*)d_out;
    int n = in_sizes[0] / 4;  // points is (N, 4) flat

    int block = 256;
    int grid = (n + block - 1) / block;
    voxelize_kernel<<<grid, block, 0, stream>>>(points, out, n);
}